// Round 4
// baseline (629.276 us; speedup 1.0000x reference)
//
#include <hip/hip_runtime.h>

// Problem constants
#define LQN   16384     // queries per batch (128*128)
#define LINN  65536     // value length per batch (4 levels * 16384)

typedef __attribute__((ext_vector_type(8))) short bf16x8;
typedef __attribute__((ext_vector_type(4))) float f32x4;
typedef __attribute__((ext_vector_type(4))) unsigned short bf16x4;

__device__ __forceinline__ unsigned short f2bf(float f) {
  unsigned u = __float_as_uint(f);
  u += 0x7FFFu + ((u >> 16) & 1u);      // round-to-nearest-even
  return (unsigned short)(u >> 16);
}

// ---------------- fused weight transpose+convert for all 6 weights.
// wt layout (shorts): W_val[0,65536) W_off[65536,131072) W_attn[131072,163840)
// W_out[163840,229376) W1[229376,491520) W2[491520,753664). Total 753664.
// NOTE: W_off then W_attn contiguous => combined 384xK matrix for the merged GEMM.
__global__ __launch_bounds__(256) void wtrans6_kernel(
    const float* __restrict__ Wv, const float* __restrict__ Wo,
    const float* __restrict__ Wa, const float* __restrict__ Wu,
    const float* __restrict__ W1, const float* __restrict__ W2,
    unsigned short* __restrict__ wt) {
  int idx = blockIdx.x * 256 + threadIdx.x;     // grid = 2944 blocks exactly
  const float* W; int K, N, base;
  if (idx < 131072) {
    if (idx < 65536) { W = Wv; K = 256; N = 256; base = 0; }
    else             { W = Wo; K = 256; N = 256; base = 65536; }
  } else if (idx < 229376) {
    if (idx < 163840) { W = Wa; K = 256; N = 128; base = 131072; }
    else              { W = Wu; K = 256; N = 256; base = 163840; }
  } else if (idx < 491520) { W = W1; K = 256; N = 1024; base = 229376; }
  else                     { W = W2; K = 1024; N = 256; base = 491520; }
  int local = idx - base;
  int n = local / K, k = local - n * K;
  wt[idx] = f2bf(W[(size_t)k * N + n]);
}

// ---------------- streaming add+convert (v3, 4x ILP):
// inp_bf = bf16(src_all + pos_flat); level-3 blocks also produce
// qbuf = bf16(cur_src + pos[:,3]) reusing the loaded pos register.
// Each thread handles 4 float4-pairs; all loads issued before dependent use
// (the kernel was latency-bound at 2 outstanding loads: 2.2 of 6.3 TB/s).
// Block covers 1024 consecutive float4s; level-3 membership is block-uniform.
__global__ __launch_bounds__(256) void addcvt_kernel(
    const float* __restrict__ src_all, const float* __restrict__ pos,
    const float* __restrict__ cur, unsigned short* __restrict__ inp_bf,
    unsigned short* __restrict__ qb) {
  const size_t i0 = (size_t)blockIdx.x * 1024;        // grid 8192 blocks
  const size_t base = i0 + threadIdx.x;
  const bool lvl3 = ((i0 & 4194303) >= 3145728);      // uniform per block
  float4 a[4], b[4];
#pragma unroll
  for (int k = 0; k < 4; k++) {
    a[k] = ((const float4*)src_all)[base + k * 256];
    b[k] = ((const float4*)pos)[base + k * 256];
  }
  if (!lvl3) {
#pragma unroll
    for (int k = 0; k < 4; k++) {
      bf16x4 o;
      o.x = f2bf(a[k].x + b[k].x); o.y = f2bf(a[k].y + b[k].y);
      o.z = f2bf(a[k].z + b[k].z); o.w = f2bf(a[k].w + b[k].w);
      ((bf16x4*)inp_bf)[base + k * 256] = o;
    }
  } else {
    float4 c[4];
    size_t jq[4];
#pragma unroll
    for (int k = 0; k < 4; k++) {
      const size_t i = base + k * 256;
      jq[k] = (i >> 22) * 1048576 + ((i & 4194303) - 3145728);
      c[k] = ((const float4*)cur)[jq[k]];
    }
#pragma unroll
    for (int k = 0; k < 4; k++) {
      bf16x4 o;
      o.x = f2bf(a[k].x + b[k].x); o.y = f2bf(a[k].y + b[k].y);
      o.z = f2bf(a[k].z + b[k].z); o.w = f2bf(a[k].w + b[k].w);
      ((bf16x4*)inp_bf)[base + k * 256] = o;
      bf16x4 o2;
      o2.x = f2bf(c[k].x + b[k].x); o2.y = f2bf(c[k].y + b[k].y);
      o2.z = f2bf(c[k].z + b[k].z); o2.w = f2bf(c[k].w + b[k].w);
      ((bf16x4*)qb)[jq[k]] = o2;
    }
  }
}

// ---------------- bf16 MFMA GEMM, m97-style global_load_lds staging.
// A: M x K bf16 row-major. Bt: N x K bf16 (pre-transposed). 128x128 tile,
// BK=64, 4 waves (2x2 of 64x64). LDS unpadded, XOR source-swizzle: physical
// 16B chunk p of row r holds logical chunk p^(r&7); reads become 2-way (free).
// 1D grid, y-fast: by = bid % ny (N tile), bx = bid / ny (M tile).
// SPLIT=1: cols [0,256) -> Cp (stride 256) + bias, cols [256,384) -> Cp2
// (stride 128) + bias2 (block-uniform branch; tiles are pure).
// OUT_VAL=1: bf16 store transposed to value layout (n, h, pix, 32ch):
// addr = (((row>>16)*8 + (col>>5))*65536 + (row&65535))*32 + (col&31).
template <int DO_RELU, int OUT_BF16, int SPLIT, int OUT_VAL>
__global__ __launch_bounds__(256) void gemm_lds_kernel(
    const unsigned short* __restrict__ A, const unsigned short* __restrict__ Bt,
    const float* __restrict__ bias, const float* __restrict__ bias2,
    void* __restrict__ Cp, float* __restrict__ Cp2,
    int M, int N, int K, int ny) {
  __shared__ unsigned short As[128 * 64];
  __shared__ unsigned short Bs[128 * 64];
  const int bid = blockIdx.x;
  const int by = bid % ny, bx = bid / ny;
  const int m0 = bx * 128, n0 = by * 128;
  const int tid = threadIdx.x;
  const int wave = tid >> 6, lane = tid & 63;
  const int wm = (wave >> 1) * 64, wn = (wave & 1) * 64;
  const int l15 = lane & 15, quad = lane >> 4;
  const int rl = lane >> 3;                 // row within 8-row slab
  const int cl = (lane & 7) ^ rl;           // swizzled source chunk (16B units)

  f32x4 acc[4][4];
#pragma unroll
  for (int i = 0; i < 4; i++)
#pragma unroll
    for (int j = 0; j < 4; j++)
#pragma unroll
      for (int r = 0; r < 4; r++) acc[i][j][r] = 0.f;

  const unsigned short* Abase = A + (size_t)m0 * K + cl * 8;
  const unsigned short* Bbase = Bt + (size_t)n0 * K + cl * 8;

  for (int k0 = 0; k0 < K; k0 += 64) {
    // ---- async stage: each wave covers 32 rows of As and Bs (4 issues each)
#pragma unroll
    for (int t = 0; t < 4; t++) {
      const int row = wave * 32 + t * 8 + rl;
      __builtin_amdgcn_global_load_lds(
          (const __attribute__((address_space(1))) void*)(Abase + (size_t)row * K + k0),
          (__attribute__((address_space(3))) void*)(As + (wave * 32 + t * 8) * 64),
          16, 0, 0);
      __builtin_amdgcn_global_load_lds(
          (const __attribute__((address_space(1))) void*)(Bbase + (size_t)row * K + k0),
          (__attribute__((address_space(3))) void*)(Bs + (wave * 32 + t * 8) * 64),
          16, 0, 0);
    }
    __syncthreads();   // drains vmcnt(0) then barrier: LDS tiles ready
#pragma unroll
    for (int kk = 0; kk < 2; kk++) {
      bf16x8 af[4], bfr[4];
#pragma unroll
      for (int i = 0; i < 4; i++) {
        const int row = wm + i * 16 + l15;
        af[i] = *(const bf16x8*)&As[row * 64 + (((quad + 4 * kk) ^ (row & 7)) * 8)];
      }
#pragma unroll
      for (int j = 0; j < 4; j++) {
        const int row = wn + j * 16 + l15;
        bfr[j] = *(const bf16x8*)&Bs[row * 64 + (((quad + 4 * kk) ^ (row & 7)) * 8)];
      }
#pragma unroll
      for (int i = 0; i < 4; i++)
#pragma unroll
        for (int j = 0; j < 4; j++)
          acc[i][j] = __builtin_amdgcn_mfma_f32_16x16x32_bf16(af[i], bfr[j], acc[i][j], 0, 0, 0);
    }
    __syncthreads();   // protect LDS before next-iter overwrite
  }
  // ---- epilogue: bias (+relu), store
#pragma unroll
  for (int i = 0; i < 4; i++) {
#pragma unroll
    for (int j = 0; j < 4; j++) {
      const int col = n0 + wn + j * 16 + l15;
      float bv;
      if (SPLIT) bv = (col < 256) ? bias[col] : bias2[col - 256];
      else       bv = bias[col];
#pragma unroll
      for (int r = 0; r < 4; r++) {
        const int row = m0 + wm + i * 16 + quad * 4 + r;
        float v = acc[i][j][r] + bv;
        if (DO_RELU) v = fmaxf(v, 0.f);
        if (SPLIT) {
          if (col < 256) ((float*)Cp)[(size_t)row * 256 + col] = v;
          else           Cp2[(size_t)row * 128 + (col - 256)] = v;
        } else if (OUT_BF16) {
          size_t addr;
          if (OUT_VAL)
            addr = (((size_t)(row >> 16) * 8 + (col >> 5)) * 65536 +
                    (size_t)(row & 65535)) * 32 + (col & 31);
          else
            addr = (size_t)row * N + col;
          ((unsigned short*)Cp)[addr] = f2bf(v);
        } else {
          ((float*)Cp)[(size_t)row * N + col] = v;
        }
      }
    }
  }
}

// ---------------- deformable sampling (v3)
// value: (2, 8, LINN, 32) bf16  [head-major layout!]; offs: (2,LQ,8,4,4,2) f32;
// attnl: (2,LQ,128) f32; refp: (2,LQ,4,2) f32; out: (2,LQ,8,32) bf16.
// 8-lane subgroup per (n,lq,h). Block ordering is HEAD-MAJOR (all resident
// blocks sample the same head's 8 MiB slice -> per-XCD L2 working set 8x
// smaller). Per bilinear row the (x0,x0+1) pixel pair is one contiguous
// 128 B segment: one dwordx4 per lane, lanes 0-3 get left pixel channels,
// 4-7 right pixel; final channel combine via shfl_xor(.,4). LDS row stride
// 132 floats -> broadcast ds_read_b128 conflict-free across subgroups.
__global__ __launch_bounds__(256) void sample_kernel(
    const unsigned short* __restrict__ value, const float* __restrict__ offs,
    const float* __restrict__ attnl, const float* __restrict__ refp,
    unsigned int* __restrict__ attn_out) {
  __shared__ float wlds[32][132];
  const int tid = threadIdx.x;
  const int sub = tid >> 3;                // 0..31
  const int cl  = tid & 7;                 // lane in subgroup
  const int gb = blockIdx.x * 32 + sub;    // head-major linear id, < 262144
  const int h  = gb >> 15;                 // head (uniform per block)
  const int nl = gb & 32767;               // n*LQ + lq
  const int n  = nl >> 14;
  const int g  = nl * 8 + h;               // row id in offs / attn_out

  // ---- distributed softmax over 16 (level,point) logits; lane owns 2cl,2cl+1
  const float* lg = attnl + (size_t)nl * 128 + h * 16;
  const float2 l2 = *(const float2*)(lg + 2 * cl);
  float mx = fmaxf(l2.x, l2.y);
#pragma unroll
  for (int o = 1; o < 8; o <<= 1) mx = fmaxf(mx, __shfl_xor(mx, o, 8));
  const float e0 = __expf(l2.x - mx), e1 = __expf(l2.y - mx);
  float s = e0 + e1;
#pragma unroll
  for (int o = 1; o < 8; o <<= 1) s += __shfl_xor(s, o, 8);
  const float inv = 1.f / s;

  // ---- prep 2 points per lane (pt = 2cl, 2cl+1; both in level cl>>1) -> LDS
  const float4 o4 = *(const float4*)(offs + (size_t)g * 32 + 4 * cl);
  const float2 r2 = *(const float2*)(refp + ((size_t)nl * 4 + (cl >> 1)) * 2);
#pragma unroll
  for (int q = 0; q < 2; q++) {
    const float ox = (q == 0) ? o4.x : o4.z;
    const float oy = (q == 0) ? o4.y : o4.w;
    const float aw = ((q == 0) ? e0 : e1) * inv;
    const float x = fmaf(r2.x, 128.f, ox - 0.5f);   // (ref + off/128)*128 - 0.5
    const float y = fmaf(r2.y, 128.f, oy - 0.5f);
    const float xf = floorf(x), yf = floorf(y);
    const float fx = x - xf, fy = y - yf;
    const int x0 = (int)xf, y0 = (int)yf;
    const float wx0 = (x0 >= 0 && x0 <= 127) ? (1.f - fx) : 0.f;
    const float wx1 = (x0 >= -1 && x0 <= 126) ? fx : 0.f;
    const float wy0 = ((y0 >= 0 && y0 <= 127) ? (1.f - fy) : 0.f) * aw;
    const float wy1 = ((y0 >= -1 && y0 <= 126) ? fy : 0.f) * aw;
    // pixel pair (px, px+1) always within the row; corner weights remapped
    const int px = min(max(x0, 0), 126);
    const float wl = (px == x0) ? wx0 : ((px == x0 + 1) ? wx1 : 0.f);
    const float wr = (px + 1 == x0) ? wx0 : ((px == x0) ? wx1 : 0.f);
    const int yc0 = min(max(y0, 0), 127), yc1 = min(max(y0 + 1, 0), 127);
    const int lb = (cl >> 1) * 16384;
    const unsigned ot = (unsigned)(lb + yc0 * 128 + px) * 64u;  // byte offsets
    const unsigned ob = (unsigned)(lb + yc1 * 128 + px) * 64u;
    float* wp = &wlds[sub][(2 * cl + q) * 8];
    wp[0] = wl * wy0; wp[1] = wr * wy0;
    wp[2] = wl * wy1; wp[3] = wr * wy1;
    wp[4] = __uint_as_float(ot); wp[5] = __uint_as_float(ob);
  }
  // subgroup == 8 lanes of one wave: wave-synchronous, no barrier needed

  // ---- gather loop: 16 points x 2 rows, one dwordx4 (128 B/subgroup) each
  const char* hb = (const char*)value + (((size_t)(n * 8 + h)) << 22) + cl * 16;
  float a0 = 0.f, a1 = 0.f, a2 = 0.f, a3 = 0.f;
  float a4 = 0.f, a5 = 0.f, a6 = 0.f, a7 = 0.f;
#pragma unroll
  for (int p = 0; p < 16; p++) {
    const float4 w4 = *(const float4*)&wlds[sub][p * 8];
    const float2 of2 = *(const float2*)&wlds[sub][p * 8 + 4];
    const uint4 vt = *(const uint4*)(hb + __float_as_uint(of2.x));
    const uint4 vb = *(const uint4*)(hb + __float_as_uint(of2.y));
    const float wtop = (cl < 4) ? w4.x : w4.y;   // top row: left/right weight
    const float wbot = (cl < 4) ? w4.z : w4.w;   // bottom row
#define ACC8(vv, wgt)                                              \
    a0 = fmaf(wgt, __uint_as_float((vv).x << 16), a0);             \
    a1 = fmaf(wgt, __uint_as_float((vv).x & 0xFFFF0000u), a1);     \
    a2 = fmaf(wgt, __uint_as_float((vv).y << 16), a2);             \
    a3 = fmaf(wgt, __uint_as_float((vv).y & 0xFFFF0000u), a3);     \
    a4 = fmaf(wgt, __uint_as_float((vv).z << 16), a4);             \
    a5 = fmaf(wgt, __uint_as_float((vv).z & 0xFFFF0000u), a5);     \
    a6 = fmaf(wgt, __uint_as_float((vv).w << 16), a6);             \
    a7 = fmaf(wgt, __uint_as_float((vv).w & 0xFFFF0000u), a7);
    ACC8(vt, wtop)
    ACC8(vb, wbot)
#undef ACC8
  }
  // combine left/right pixel halves: lanes 0-3 end with full channel sums
  a0 += __shfl_xor(a0, 4, 8); a1 += __shfl_xor(a1, 4, 8);
  a2 += __shfl_xor(a2, 4, 8); a3 += __shfl_xor(a3, 4, 8);
  a4 += __shfl_xor(a4, 4, 8); a5 += __shfl_xor(a5, 4, 8);
  a6 += __shfl_xor(a6, 4, 8); a7 += __shfl_xor(a7, 4, 8);
  if (cl < 4) {
    uint4 o;
    o.x = (unsigned)f2bf(a0) | ((unsigned)f2bf(a1) << 16);
    o.y = (unsigned)f2bf(a2) | ((unsigned)f2bf(a3) << 16);
    o.z = (unsigned)f2bf(a4) | ((unsigned)f2bf(a5) << 16);
    o.w = (unsigned)f2bf(a6) | ((unsigned)f2bf(a7) << 16);
    ((uint4*)attn_out)[(size_t)g * 4 + cl] = o;
  }
}

// ---------------- layer norm over 256: out = LN(x1 + x2) * gamma + beta
// 256 threads = 4 waves, TWO rows per wave (4 loads in flight for MLP).
// Optionally also emits bf16 copy.
template <int EMIT_BF16>
__global__ __launch_bounds__(256) void ln_kernel(const float* __restrict__ x1,
                                                 const float* __restrict__ x2,
                                                 const float* __restrict__ gamma,
                                                 const float* __restrict__ beta,
                                                 float* __restrict__ out,
                                                 unsigned short* __restrict__ outb) {
  const int row0 = blockIdx.x * 8 + (threadIdx.x >> 6) * 2;   // grid 4096
  const int lane = threadIdx.x & 63;
  float4 aA = ((const float4*)(x1 + (size_t)row0 * 256))[lane];
  float4 bA = ((const float4*)(x2 + (size_t)row0 * 256))[lane];
  float4 aB = ((const float4*)(x1 + (size_t)(row0 + 1) * 256))[lane];
  float4 bB = ((const float4*)(x2 + (size_t)(row0 + 1) * 256))[lane];
  float4 gm = ((const float4*)gamma)[lane];
  float4 bt = ((const float4*)beta)[lane];
  float uA0 = aA.x + bA.x, uA1 = aA.y + bA.y, uA2 = aA.z + bA.z, uA3 = aA.w + bA.w;
  float uB0 = aB.x + bB.x, uB1 = aB.y + bB.y, uB2 = aB.z + bB.z, uB3 = aB.w + bB.w;
  float sA1 = uA0 + uA1 + uA2 + uA3;
  float sA2 = uA0 * uA0 + uA1 * uA1 + uA2 * uA2 + uA3 * uA3;
  float sB1 = uB0 + uB1 + uB2 + uB3;
  float sB2 = uB0 * uB0 + uB1 * uB1 + uB2 * uB2 + uB3 * uB3;
#pragma unroll
  for (int o = 1; o < 64; o <<= 1) {
    sA1 += __shfl_xor(sA1, o); sA2 += __shfl_xor(sA2, o);
    sB1 += __shfl_xor(sB1, o); sB2 += __shfl_xor(sB2, o);
  }
  const float meanA = sA1 * (1.f / 256.f);
  const float rstdA = rsqrtf(sA2 * (1.f / 256.f) - meanA * meanA + 1e-5f);
  const float meanB = sB1 * (1.f / 256.f);
  const float rstdB = rsqrtf(sB2 * (1.f / 256.f) - meanB * meanB + 1e-5f);
  float4 oA, oB;
  oA.x = (uA0 - meanA) * rstdA * gm.x + bt.x;
  oA.y = (uA1 - meanA) * rstdA * gm.y + bt.y;
  oA.z = (uA2 - meanA) * rstdA * gm.z + bt.z;
  oA.w = (uA3 - meanA) * rstdA * gm.w + bt.w;
  oB.x = (uB0 - meanB) * rstdB * gm.x + bt.x;
  oB.y = (uB1 - meanB) * rstdB * gm.y + bt.y;
  oB.z = (uB2 - meanB) * rstdB * gm.z + bt.z;
  oB.w = (uB3 - meanB) * rstdB * gm.w + bt.w;
  ((float4*)(out + (size_t)row0 * 256))[lane] = oA;
  ((float4*)(out + (size_t)(row0 + 1) * 256))[lane] = oB;
  if (EMIT_BF16) {
    bf16x4 obA, obB;
    obA.x = f2bf(oA.x); obA.y = f2bf(oA.y); obA.z = f2bf(oA.z); obA.w = f2bf(oA.w);
    obB.x = f2bf(oB.x); obB.y = f2bf(oB.y); obB.z = f2bf(oB.z); obB.w = f2bf(oB.w);
    ((bf16x4*)(outb + (size_t)row0 * 256))[lane] = obA;
    ((bf16x4*)(outb + (size_t)(row0 + 1) * 256))[lane] = obB;
  }
}

extern "C" void kernel_launch(void* const* d_in, const int* in_sizes, int n_in,
                              void* d_out, int out_size, void* d_ws, size_t ws_size,
                              hipStream_t stream) {
  (void)in_sizes; (void)n_in; (void)out_size; (void)ws_size;
  const float* cur_src = (const float*)d_in[0];
  const float* src_all = (const float*)d_in[1];
  const float* pos     = (const float*)d_in[2];
  const float* refp    = (const float*)d_in[3];
  const float* W_off   = (const float*)d_in[6];
  const float* b_off   = (const float*)d_in[7];
  const float* W_attn  = (const float*)d_in[8];
  const float* b_attn  = (const float*)d_in[9];
  const float* W_val   = (const float*)d_in[10];
  const float* b_val   = (const float*)d_in[11];
  const float* W_out   = (const float*)d_in[12];
  const float* b_out   = (const float*)d_in[13];
  const float* gamma1  = (const float*)d_in[14];
  const float* beta1   = (const float*)d_in[15];
  const float* W1      = (const float*)d_in[16];
  const float* b1      = (const float*)d_in[17];
  const float* W2      = (const float*)d_in[18];
  const float* b2      = (const float*)d_in[19];
  const float* gamma2  = (const float*)d_in[20];
  const float* beta2   = (const float*)d_in[21];
  float* out = (float*)d_out;

  // workspace layout (bytes); total ~209.4 MiB (unchanged)
  char* ws = (char*)d_ws;
  unsigned short* value = (unsigned short*)(ws + 0);          // 67,108,864 B; reused as FFN hidden
  unsigned short* qbuf  = (unsigned short*)(ws + 67108864);   // 16,777,216 B
  float* offbuf         = (float*)(ws + 83886080);            // 33,554,432 B; reused as ffn_out
  float* attnl          = (float*)(ws + 117440512);           // 16,777,216 B; reused as srcb_bf16
  unsigned short* attno = (unsigned short*)(ws + 134217728);  // 16,777,216 B
  float* src2           = (float*)(ws + 150994944);           // 33,554,432 B
  float* srcb           = (float*)(ws + 184549376);           // 33,554,432 B
  unsigned short* wt    = (unsigned short*)(ws + 218103808);  // bf16 weights (1.5 MB)
  unsigned short* wt_val  = wt;
  unsigned short* wt_qa   = wt + 65536;   // W_off(256xK) ++ W_attn(128xK) contiguous
  unsigned short* wt_out  = wt + 163840;
  unsigned short* wt_1    = wt + 229376;
  unsigned short* wt_2    = wt + 491520;
  unsigned short* srcb_bf = (unsigned short*)attnl;           // attnl dead after sample
  // inp_bf (131072x256 bf16 = 64 MiB) overlays src2+srcb (dead until out-proj)
  unsigned short* inp_bf  = (unsigned short*)src2;

  // prep: all weights -> bf16 NxK in one launch
  wtrans6_kernel<<<2944, 256, 0, stream>>>(W_val, W_off, W_attn, W_out, W1, W2, wt);

  // inp_bf = bf16(src_all + pos_flat); level-3 blocks also emit qbuf (4x ILP)
  addcvt_kernel<<<8192, 256, 0, stream>>>(src_all, pos, cur_src, inp_bf, qbuf);

  // value = inp_bf @ W_val + b_val -> bf16, stored head-major (n,h,pix,ch)
  gemm_lds_kernel<0, 1, 0, 1><<<2048, 256, 0, stream>>>(
      inp_bf, wt_val, b_val, nullptr, value, nullptr, 131072, 256, 256, 2);
  // [off | attn logits] = qbuf @ [W_off | W_attn] (merged N=384, split epilogue)
  gemm_lds_kernel<0, 0, 1, 0><<<768, 256, 0, stream>>>(
      qbuf, wt_qa, b_off, b_attn, offbuf, attnl, 32768, 384, 256, 3);
  // deformable sampling -> attn_out bf16 (head-major block order)
  sample_kernel<<<8192, 256, 0, stream>>>(value, offbuf, attnl, refp,
                                          (unsigned int*)attno);
  // src2 = attn_out @ W_out + b_out (f32)  [overwrites inp_bf region: dead]
  gemm_lds_kernel<0, 0, 0, 0><<<512, 256, 0, stream>>>(
      attno, wt_out, b_out, nullptr, src2, nullptr, 32768, 256, 256, 2);
  // src = LN(cur_src + src2) -> f32 srcb + bf16 srcb_bf
  ln_kernel<1><<<4096, 256, 0, stream>>>(cur_src, src2, gamma1, beta1, srcb, srcb_bf);
  // h = relu(src @ W1 + b1) -> bf16 (reuses value buffer; sample already done)
  gemm_lds_kernel<1, 1, 0, 0><<<2048, 256, 0, stream>>>(
      srcb_bf, wt_1, b1, nullptr, value, nullptr, 32768, 1024, 256, 8);
  // ffn_out = h @ W2 + b2 (f32, reuses offbuf)
  gemm_lds_kernel<0, 0, 0, 0><<<512, 256, 0, stream>>>(
      value, wt_2, b2, nullptr, offbuf, nullptr, 32768, 256, 1024, 2);
  // out = LN(src + ffn_out)
  ln_kernel<0><<<4096, 256, 0, stream>>>(srcb, offbuf, gamma2, beta2, out, nullptr);
}

// Round 5
// 605.854 us; speedup vs baseline: 1.0387x; 1.0387x over previous
//
#include <hip/hip_runtime.h>

// Problem constants
#define LQN   16384     // queries per batch (128*128)
#define LINN  65536     // value length per batch (4 levels * 16384)

typedef __attribute__((ext_vector_type(8))) short bf16x8;
typedef __attribute__((ext_vector_type(4))) float f32x4;
typedef __attribute__((ext_vector_type(4))) unsigned short bf16x4;

__device__ __forceinline__ unsigned short f2bf(float f) {
  unsigned u = __float_as_uint(f);
  u += 0x7FFFu + ((u >> 16) & 1u);      // round-to-nearest-even
  return (unsigned short)(u >> 16);
}
__device__ __forceinline__ unsigned pk2bf(float lo, float hi) {
  return (unsigned)f2bf(lo) | ((unsigned)f2bf(hi) << 16);
}

// ---------------- fused weight transpose+convert for all 6 weights.
// wt layout (shorts): W_val[0,65536) W_off[65536,131072) W_attn[131072,163840)
// W_out[163840,229376) W1[229376,491520) W2[491520,753664). Total 753664.
// NOTE: W_off then W_attn contiguous => combined 384xK matrix for the merged GEMM.
__global__ __launch_bounds__(256) void wtrans6_kernel(
    const float* __restrict__ Wv, const float* __restrict__ Wo,
    const float* __restrict__ Wa, const float* __restrict__ Wu,
    const float* __restrict__ W1, const float* __restrict__ W2,
    unsigned short* __restrict__ wt) {
  int idx = blockIdx.x * 256 + threadIdx.x;     // grid = 2944 blocks exactly
  const float* W; int K, N, base;
  if (idx < 131072) {
    if (idx < 65536) { W = Wv; K = 256; N = 256; base = 0; }
    else             { W = Wo; K = 256; N = 256; base = 65536; }
  } else if (idx < 229376) {
    if (idx < 163840) { W = Wa; K = 256; N = 128; base = 131072; }
    else              { W = Wu; K = 256; N = 256; base = 163840; }
  } else if (idx < 491520) { W = W1; K = 256; N = 1024; base = 229376; }
  else                     { W = W2; K = 1024; N = 256; base = 491520; }
  int local = idx - base;
  int n = local / K, k = local - n * K;
  wt[idx] = f2bf(W[(size_t)k * N + n]);
}

// ---------------- qbuf = bf16(cur_src + pos[:,3]) only (84 MB streaming).
// (flat inp_bf production is now fused into the value GEMM)
__global__ __launch_bounds__(256) void addcvt_q_kernel(
    const float* __restrict__ cur, const float* __restrict__ pos,
    unsigned short* __restrict__ qb) {
  size_t j = (size_t)blockIdx.x * 256 + threadIdx.x;  // < 2,097,152 (grid 8192)
  size_t row = j >> 6;                    // n*LQ + lq
  int n = (int)(row >> 14), lq = (int)(row & 16383);
  float4 a = ((const float4*)cur)[j];
  float4 b = ((const float4*)pos)[(((size_t)n * 4 + 3) * LQN + lq) * 64 + (j & 63)];
  bf16x4 o;
  o.x = f2bf(a.x + b.x); o.y = f2bf(a.y + b.y);
  o.z = f2bf(a.z + b.z); o.w = f2bf(a.w + b.w);
  ((bf16x4*)qb)[j] = o;
}

// ---------------- fused value GEMM:
// value = bf16(src_all + pos_flat) @ Wv + bv, stored head-major (n,h,pix,32ch).
// M=131072, N=256 (FULL width per block -> f32 A-panels read exactly once),
// K=256, BK=64, 512 threads = 8 waves (2 M-groups x 4 N-groups of 64x64).
// A: reg-staged add+cvt (f32+f32 -> bf16) written to XOR-swizzled LDS
//    (logical chunk c of row r at physical chunk c^(r&7), same as reader).
// B: global_load_lds with XOR source-swizzle (identical to gemm_lds_kernel).
__global__ __launch_bounds__(512) void gemmv_fused_kernel(
    const float* __restrict__ SA, const float* __restrict__ PS,
    const unsigned short* __restrict__ Bt, const float* __restrict__ bias,
    unsigned short* __restrict__ Cp) {
  __shared__ unsigned short As[128 * 64];   // 16 KB
  __shared__ unsigned short Bs[256 * 64];   // 32 KB
  const int m0 = blockIdx.x * 128;          // grid 1024
  const int tid = threadIdx.x;
  const int wave = tid >> 6, lane = tid & 63;
  const int wm = (wave >> 2) * 64;          // 0 or 64
  const int wn = (wave & 3) * 64;           // 0,64,128,192
  const int l15 = lane & 15, quad = lane >> 4;
  const int rl = lane >> 3;                 // row within 8-row slab (B staging)
  const int cl = (lane & 7) ^ rl;           // XOR source chunk (B staging)

  // A staging coords: wave stages rows wave*16..+15; lane owns 2 chunks
  const int ar = wave * 16 + (lane >> 2);   // tile row 0..127
  const int cb = (lane & 3) * 2;            // first of 2 owned chunks (8 bf16 ea)
  const float* pa = SA + (size_t)(m0 + ar) * 256 + cb * 8;
  const float* pb = PS + (size_t)(m0 + ar) * 256 + cb * 8;

  const unsigned short* Bbase = Bt + cl * 8;

  f32x4 acc[4][4];
#pragma unroll
  for (int i = 0; i < 4; i++)
#pragma unroll
    for (int j = 0; j < 4; j++)
#pragma unroll
      for (int r = 0; r < 4; r++) acc[i][j][r] = 0.f;

  for (int k0 = 0; k0 < 256; k0 += 64) {
    // ---- B tile: async global->LDS, wave covers 32 rows (4 issues of 8)
#pragma unroll
    for (int t = 0; t < 4; t++) {
      const int row = wave * 32 + t * 8 + rl;
      __builtin_amdgcn_global_load_lds(
          (const __attribute__((address_space(1))) void*)(Bbase + (size_t)row * 256 + k0),
          (__attribute__((address_space(3))) void*)(Bs + (wave * 32 + t * 8) * 64),
          16, 0, 0);
    }
    // ---- A tile: load 16 f32 from each source, add, cvt, swizzled ds_write
    float4 fa[4], fb[4];
#pragma unroll
    for (int u = 0; u < 4; u++) fa[u] = ((const float4*)(pa + k0))[u];
#pragma unroll
    for (int u = 0; u < 4; u++) fb[u] = ((const float4*)(pb + k0))[u];
#pragma unroll
    for (int c = 0; c < 2; c++) {
      uint4 wv;
      wv.x = pk2bf(fa[2 * c].x + fb[2 * c].x, fa[2 * c].y + fb[2 * c].y);
      wv.y = pk2bf(fa[2 * c].z + fb[2 * c].z, fa[2 * c].w + fb[2 * c].w);
      wv.z = pk2bf(fa[2 * c + 1].x + fb[2 * c + 1].x, fa[2 * c + 1].y + fb[2 * c + 1].y);
      wv.w = pk2bf(fa[2 * c + 1].z + fb[2 * c + 1].z, fa[2 * c + 1].w + fb[2 * c + 1].w);
      const int p = (cb + c) ^ (ar & 7);
      *(uint4*)((char*)As + ar * 128 + p * 16) = wv;
    }
    __syncthreads();   // drains vmcnt (B) + lgkm (A writes), then barrier
#pragma unroll
    for (int kk = 0; kk < 2; kk++) {
      bf16x8 af[4], bfr[4];
#pragma unroll
      for (int i = 0; i < 4; i++) {
        const int row = wm + i * 16 + l15;
        af[i] = *(const bf16x8*)&As[row * 64 + (((quad + 4 * kk) ^ (row & 7)) * 8)];
      }
#pragma unroll
      for (int j = 0; j < 4; j++) {
        const int row = wn + j * 16 + l15;
        bfr[j] = *(const bf16x8*)&Bs[row * 64 + (((quad + 4 * kk) ^ (row & 7)) * 8)];
      }
#pragma unroll
      for (int i = 0; i < 4; i++)
#pragma unroll
        for (int j = 0; j < 4; j++)
          acc[i][j] = __builtin_amdgcn_mfma_f32_16x16x32_bf16(af[i], bfr[j], acc[i][j], 0, 0, 0);
    }
    __syncthreads();   // protect LDS before next-iter overwrite
  }
  // ---- epilogue: bias, head-major scatter store
#pragma unroll
  for (int i = 0; i < 4; i++) {
#pragma unroll
    for (int j = 0; j < 4; j++) {
      const int col = wn + j * 16 + l15;
      const float bv = bias[col];
#pragma unroll
      for (int r = 0; r < 4; r++) {
        const int row = m0 + wm + i * 16 + quad * 4 + r;
        const float v = acc[i][j][r] + bv;
        const size_t addr = (((size_t)(row >> 16) * 8 + (col >> 5)) * 65536 +
                             (size_t)(row & 65535)) * 32 + (col & 31);
        Cp[addr] = f2bf(v);
      }
    }
  }
}

// ---------------- bf16 MFMA GEMM, m97-style global_load_lds staging.
// A: M x K bf16 row-major. Bt: N x K bf16 (pre-transposed). 128x128 tile,
// BK=64, 4 waves (2x2 of 64x64). LDS unpadded, XOR source-swizzle.
// SPLIT=1: cols [0,256) -> Cp (stride 256) + bias, cols [256,384) -> Cp2.
template <int DO_RELU, int OUT_BF16, int SPLIT>
__global__ __launch_bounds__(256) void gemm_lds_kernel(
    const unsigned short* __restrict__ A, const unsigned short* __restrict__ Bt,
    const float* __restrict__ bias, const float* __restrict__ bias2,
    void* __restrict__ Cp, float* __restrict__ Cp2,
    int M, int N, int K, int ny) {
  __shared__ unsigned short As[128 * 64];
  __shared__ unsigned short Bs[128 * 64];
  const int bid = blockIdx.x;
  const int by = bid % ny, bx = bid / ny;
  const int m0 = bx * 128, n0 = by * 128;
  const int tid = threadIdx.x;
  const int wave = tid >> 6, lane = tid & 63;
  const int wm = (wave >> 1) * 64, wn = (wave & 1) * 64;
  const int l15 = lane & 15, quad = lane >> 4;
  const int rl = lane >> 3;                 // row within 8-row slab
  const int cl = (lane & 7) ^ rl;           // swizzled source chunk (16B units)

  f32x4 acc[4][4];
#pragma unroll
  for (int i = 0; i < 4; i++)
#pragma unroll
    for (int j = 0; j < 4; j++)
#pragma unroll
      for (int r = 0; r < 4; r++) acc[i][j][r] = 0.f;

  const unsigned short* Abase = A + (size_t)m0 * K + cl * 8;
  const unsigned short* Bbase = Bt + (size_t)n0 * K + cl * 8;

  for (int k0 = 0; k0 < K; k0 += 64) {
#pragma unroll
    for (int t = 0; t < 4; t++) {
      const int row = wave * 32 + t * 8 + rl;
      __builtin_amdgcn_global_load_lds(
          (const __attribute__((address_space(1))) void*)(Abase + (size_t)row * K + k0),
          (__attribute__((address_space(3))) void*)(As + (wave * 32 + t * 8) * 64),
          16, 0, 0);
      __builtin_amdgcn_global_load_lds(
          (const __attribute__((address_space(1))) void*)(Bbase + (size_t)row * K + k0),
          (__attribute__((address_space(3))) void*)(Bs + (wave * 32 + t * 8) * 64),
          16, 0, 0);
    }
    __syncthreads();
#pragma unroll
    for (int kk = 0; kk < 2; kk++) {
      bf16x8 af[4], bfr[4];
#pragma unroll
      for (int i = 0; i < 4; i++) {
        const int row = wm + i * 16 + l15;
        af[i] = *(const bf16x8*)&As[row * 64 + (((quad + 4 * kk) ^ (row & 7)) * 8)];
      }
#pragma unroll
      for (int j = 0; j < 4; j++) {
        const int row = wn + j * 16 + l15;
        bfr[j] = *(const bf16x8*)&Bs[row * 64 + (((quad + 4 * kk) ^ (row & 7)) * 8)];
      }
#pragma unroll
      for (int i = 0; i < 4; i++)
#pragma unroll
        for (int j = 0; j < 4; j++)
          acc[i][j] = __builtin_amdgcn_mfma_f32_16x16x32_bf16(af[i], bfr[j], acc[i][j], 0, 0, 0);
    }
    __syncthreads();
  }
#pragma unroll
  for (int i = 0; i < 4; i++) {
#pragma unroll
    for (int j = 0; j < 4; j++) {
      const int col = n0 + wn + j * 16 + l15;
      float bv;
      if (SPLIT) bv = (col < 256) ? bias[col] : bias2[col - 256];
      else       bv = bias[col];
#pragma unroll
      for (int r = 0; r < 4; r++) {
        const int row = m0 + wm + i * 16 + quad * 4 + r;
        float v = acc[i][j][r] + bv;
        if (DO_RELU) v = fmaxf(v, 0.f);
        if (SPLIT) {
          if (col < 256) ((float*)Cp)[(size_t)row * 256 + col] = v;
          else           Cp2[(size_t)row * 128 + (col - 256)] = v;
        } else if (OUT_BF16) {
          ((unsigned short*)Cp)[(size_t)row * N + col] = f2bf(v);
        } else {
          ((float*)Cp)[(size_t)row * N + col] = v;
        }
      }
    }
  }
}

// ---------------- deformable sampling (v3)
// value: (2, 8, LINN, 32) bf16  [head-major layout!]; offs: (2,LQ,8,4,4,2) f32;
// attnl: (2,LQ,128) f32; refp: (2,LQ,4,2) f32; out: (2,LQ,8,32) bf16.
// 8-lane subgroup per (n,lq,h). HEAD-MAJOR block order (per-XCD L2 working set
// 8x smaller). (x0,x0+1) pixel pair = one contiguous 128 B segment: one
// dwordx4 per lane; lanes 0-3 left pixel, 4-7 right; combine via shfl_xor(4).
// LDS row stride 132 floats -> conflict-free broadcast reads.
__global__ __launch_bounds__(256) void sample_kernel(
    const unsigned short* __restrict__ value, const float* __restrict__ offs,
    const float* __restrict__ attnl, const float* __restrict__ refp,
    unsigned int* __restrict__ attn_out) {
  __shared__ float wlds[32][132];
  const int tid = threadIdx.x;
  const int sub = tid >> 3;                // 0..31
  const int cl  = tid & 7;                 // lane in subgroup
  const int gb = blockIdx.x * 32 + sub;    // head-major linear id, < 262144
  const int h  = gb >> 15;                 // head (uniform per block)
  const int nl = gb & 32767;               // n*LQ + lq
  const int n  = nl >> 14;
  const int g  = nl * 8 + h;               // row id in offs / attn_out

  // ---- distributed softmax over 16 (level,point) logits; lane owns 2cl,2cl+1
  const float* lg = attnl + (size_t)nl * 128 + h * 16;
  const float2 l2 = *(const float2*)(lg + 2 * cl);
  float mx = fmaxf(l2.x, l2.y);
#pragma unroll
  for (int o = 1; o < 8; o <<= 1) mx = fmaxf(mx, __shfl_xor(mx, o, 8));
  const float e0 = __expf(l2.x - mx), e1 = __expf(l2.y - mx);
  float s = e0 + e1;
#pragma unroll
  for (int o = 1; o < 8; o <<= 1) s += __shfl_xor(s, o, 8);
  const float inv = 1.f / s;

  // ---- prep 2 points per lane (pt = 2cl, 2cl+1; both in level cl>>1) -> LDS
  const float4 o4 = *(const float4*)(offs + (size_t)g * 32 + 4 * cl);
  const float2 r2 = *(const float2*)(refp + ((size_t)nl * 4 + (cl >> 1)) * 2);
#pragma unroll
  for (int q = 0; q < 2; q++) {
    const float ox = (q == 0) ? o4.x : o4.z;
    const float oy = (q == 0) ? o4.y : o4.w;
    const float aw = ((q == 0) ? e0 : e1) * inv;
    const float x = fmaf(r2.x, 128.f, ox - 0.5f);   // (ref + off/128)*128 - 0.5
    const float y = fmaf(r2.y, 128.f, oy - 0.5f);
    const float xf = floorf(x), yf = floorf(y);
    const float fx = x - xf, fy = y - yf;
    const int x0 = (int)xf, y0 = (int)yf;
    const float wx0 = (x0 >= 0 && x0 <= 127) ? (1.f - fx) : 0.f;
    const float wx1 = (x0 >= -1 && x0 <= 126) ? fx : 0.f;
    const float wy0 = ((y0 >= 0 && y0 <= 127) ? (1.f - fy) : 0.f) * aw;
    const float wy1 = ((y0 >= -1 && y0 <= 126) ? fy : 0.f) * aw;
    // pixel pair (px, px+1) always within the row; corner weights remapped
    const int px = min(max(x0, 0), 126);
    const float wl = (px == x0) ? wx0 : ((px == x0 + 1) ? wx1 : 0.f);
    const float wr = (px + 1 == x0) ? wx0 : ((px == x0) ? wx1 : 0.f);
    const int yc0 = min(max(y0, 0), 127), yc1 = min(max(y0 + 1, 0), 127);
    const int lb = (cl >> 1) * 16384;
    const unsigned ot = (unsigned)(lb + yc0 * 128 + px) * 64u;  // byte offsets
    const unsigned ob = (unsigned)(lb + yc1 * 128 + px) * 64u;
    float* wp = &wlds[sub][(2 * cl + q) * 8];
    wp[0] = wl * wy0; wp[1] = wr * wy0;
    wp[2] = wl * wy1; wp[3] = wr * wy1;
    wp[4] = __uint_as_float(ot); wp[5] = __uint_as_float(ob);
  }
  // subgroup == 8 lanes of one wave: wave-synchronous, no barrier needed

  // ---- gather loop: 16 points x 2 rows, one dwordx4 (128 B/subgroup) each
  const char* hb = (const char*)value + (((size_t)(n * 8 + h)) << 22) + cl * 16;
  float a0 = 0.f, a1 = 0.f, a2 = 0.f, a3 = 0.f;
  float a4 = 0.f, a5 = 0.f, a6 = 0.f, a7 = 0.f;
#pragma unroll
  for (int p = 0; p < 16; p++) {
    const float4 w4 = *(const float4*)&wlds[sub][p * 8];
    const float2 of2 = *(const float2*)&wlds[sub][p * 8 + 4];
    const uint4 vt = *(const uint4*)(hb + __float_as_uint(of2.x));
    const uint4 vb = *(const uint4*)(hb + __float_as_uint(of2.y));
    const float wtop = (cl < 4) ? w4.x : w4.y;   // top row: left/right weight
    const float wbot = (cl < 4) ? w4.z : w4.w;   // bottom row
#define ACC8(vv, wgt)                                              \
    a0 = fmaf(wgt, __uint_as_float((vv).x << 16), a0);             \
    a1 = fmaf(wgt, __uint_as_float((vv).x & 0xFFFF0000u), a1);     \
    a2 = fmaf(wgt, __uint_as_float((vv).y << 16), a2);             \
    a3 = fmaf(wgt, __uint_as_float((vv).y & 0xFFFF0000u), a3);     \
    a4 = fmaf(wgt, __uint_as_float((vv).z << 16), a4);             \
    a5 = fmaf(wgt, __uint_as_float((vv).z & 0xFFFF0000u), a5);     \
    a6 = fmaf(wgt, __uint_as_float((vv).w << 16), a6);             \
    a7 = fmaf(wgt, __uint_as_float((vv).w & 0xFFFF0000u), a7);
    ACC8(vt, wtop)
    ACC8(vb, wbot)
#undef ACC8
  }
  // combine left/right pixel halves: lanes 0-3 end with full channel sums
  a0 += __shfl_xor(a0, 4, 8); a1 += __shfl_xor(a1, 4, 8);
  a2 += __shfl_xor(a2, 4, 8); a3 += __shfl_xor(a3, 4, 8);
  a4 += __shfl_xor(a4, 4, 8); a5 += __shfl_xor(a5, 4, 8);
  a6 += __shfl_xor(a6, 4, 8); a7 += __shfl_xor(a7, 4, 8);
  if (cl < 4) {
    uint4 o;
    o.x = (unsigned)f2bf(a0) | ((unsigned)f2bf(a1) << 16);
    o.y = (unsigned)f2bf(a2) | ((unsigned)f2bf(a3) << 16);
    o.z = (unsigned)f2bf(a4) | ((unsigned)f2bf(a5) << 16);
    o.w = (unsigned)f2bf(a6) | ((unsigned)f2bf(a7) << 16);
    ((uint4*)attn_out)[(size_t)g * 4 + cl] = o;
  }
}

// ---------------- layer norm over 256: out = LN(x1 + x2) * gamma + beta
// 256 threads = 4 waves, one row per wave. Optionally also emits bf16 copy.
template <int EMIT_BF16>
__global__ __launch_bounds__(256) void ln_kernel(const float* __restrict__ x1,
                                                 const float* __restrict__ x2,
                                                 const float* __restrict__ gamma,
                                                 const float* __restrict__ beta,
                                                 float* __restrict__ out,
                                                 unsigned short* __restrict__ outb) {
  const int row = blockIdx.x * 4 + (threadIdx.x >> 6);
  const int lane = threadIdx.x & 63;
  float4 a = ((const float4*)(x1 + (size_t)row * 256))[lane];
  float4 b = ((const float4*)(x2 + (size_t)row * 256))[lane];
  float v0 = a.x + b.x, v1 = a.y + b.y, v2 = a.z + b.z, v3 = a.w + b.w;
  float s1 = v0 + v1 + v2 + v3;
  float s2 = v0 * v0 + v1 * v1 + v2 * v2 + v3 * v3;
#pragma unroll
  for (int o = 1; o < 64; o <<= 1) { s1 += __shfl_xor(s1, o); s2 += __shfl_xor(s2, o); }
  const float mean = s1 * (1.f / 256.f);
  const float var = s2 * (1.f / 256.f) - mean * mean;
  const float rstd = rsqrtf(var + 1e-5f);
  float4 gm = ((const float4*)gamma)[lane];
  float4 bt = ((const float4*)beta)[lane];
  float4 o4;
  o4.x = (v0 - mean) * rstd * gm.x + bt.x;
  o4.y = (v1 - mean) * rstd * gm.y + bt.y;
  o4.z = (v2 - mean) * rstd * gm.z + bt.z;
  o4.w = (v3 - mean) * rstd * gm.w + bt.w;
  ((float4*)(out + (size_t)row * 256))[lane] = o4;
  if (EMIT_BF16) {
    bf16x4 ob;
    ob.x = f2bf(o4.x); ob.y = f2bf(o4.y); ob.z = f2bf(o4.z); ob.w = f2bf(o4.w);
    ((bf16x4*)(outb + (size_t)row * 256))[lane] = ob;
  }
}

extern "C" void kernel_launch(void* const* d_in, const int* in_sizes, int n_in,
                              void* d_out, int out_size, void* d_ws, size_t ws_size,
                              hipStream_t stream) {
  (void)in_sizes; (void)n_in; (void)out_size; (void)ws_size;
  const float* cur_src = (const float*)d_in[0];
  const float* src_all = (const float*)d_in[1];
  const float* pos     = (const float*)d_in[2];
  const float* refp    = (const float*)d_in[3];
  const float* W_off   = (const float*)d_in[6];
  const float* b_off   = (const float*)d_in[7];
  const float* W_attn  = (const float*)d_in[8];
  const float* b_attn  = (const float*)d_in[9];
  const float* W_val   = (const float*)d_in[10];
  const float* b_val   = (const float*)d_in[11];
  const float* W_out   = (const float*)d_in[12];
  const float* b_out   = (const float*)d_in[13];
  const float* gamma1  = (const float*)d_in[14];
  const float* beta1   = (const float*)d_in[15];
  const float* W1      = (const float*)d_in[16];
  const float* b1      = (const float*)d_in[17];
  const float* W2      = (const float*)d_in[18];
  const float* b2      = (const float*)d_in[19];
  const float* gamma2  = (const float*)d_in[20];
  const float* beta2   = (const float*)d_in[21];
  float* out = (float*)d_out;

  // workspace layout (bytes); total ~209.4 MiB
  char* ws = (char*)d_ws;
  unsigned short* value = (unsigned short*)(ws + 0);          // 67,108,864 B; reused as FFN hidden
  unsigned short* qbuf  = (unsigned short*)(ws + 67108864);   // 16,777,216 B
  float* offbuf         = (float*)(ws + 83886080);            // 33,554,432 B; reused as ffn_out
  float* attnl          = (float*)(ws + 117440512);           // 16,777,216 B; reused as srcb_bf16
  unsigned short* attno = (unsigned short*)(ws + 134217728);  // 16,777,216 B
  float* src2           = (float*)(ws + 150994944);           // 33,554,432 B
  float* srcb           = (float*)(ws + 184549376);           // 33,554,432 B
  unsigned short* wt    = (unsigned short*)(ws + 218103808);  // bf16 weights (1.5 MB)
  unsigned short* wt_val  = wt;
  unsigned short* wt_qa   = wt + 65536;   // W_off(256xK) ++ W_attn(128xK) contiguous
  unsigned short* wt_out  = wt + 163840;
  unsigned short* wt_1    = wt + 229376;
  unsigned short* wt_2    = wt + 491520;
  unsigned short* srcb_bf = (unsigned short*)attnl;           // attnl dead after sample

  // prep: all weights -> bf16 NxK in one launch
  wtrans6_kernel<<<2944, 256, 0, stream>>>(W_val, W_off, W_attn, W_out, W1, W2, wt);

  // qbuf = bf16(cur_src + pos[:,3])
  addcvt_q_kernel<<<8192, 256, 0, stream>>>(cur_src, pos, qbuf);

  // value = bf16(src_all + pos) @ W_val + b_val -> bf16 head-major (fused)
  gemmv_fused_kernel<<<1024, 512, 0, stream>>>(src_all, pos, wt_val, b_val, value);

  // [off | attn logits] = qbuf @ [W_off | W_attn] (merged N=384, split epilogue)
  gemm_lds_kernel<0, 0, 1><<<768, 256, 0, stream>>>(
      qbuf, wt_qa, b_off, b_attn, offbuf, attnl, 32768, 384, 256, 3);
  // deformable sampling -> attn_out bf16 (head-major block order)
  sample_kernel<<<8192, 256, 0, stream>>>(value, offbuf, attnl, refp,
                                          (unsigned int*)attno);
  // src2 = attn_out @ W_out + b_out (f32)
  gemm_lds_kernel<0, 0, 0><<<512, 256, 0, stream>>>(
      attno, wt_out, b_out, nullptr, src2, nullptr, 32768, 256, 256, 2);
  // src = LN(cur_src + src2) -> f32 srcb + bf16 srcb_bf
  ln_kernel<1><<<8192, 256, 0, stream>>>(cur_src, src2, gamma1, beta1, srcb, srcb_bf);
  // h = relu(src @ W1 + b1) -> bf16 (reuses value buffer; sample already done)
  gemm_lds_kernel<1, 1, 0><<<2048, 256, 0, stream>>>(
      srcb_bf, wt_1, b1, nullptr, value, nullptr, 32768, 1024, 256, 8);
  // ffn_out = h @ W2 + b2 (f32, reuses offbuf)
  gemm_lds_kernel<0, 0, 0><<<512, 256, 0, stream>>>(
      value, wt_2, b2, nullptr, offbuf, nullptr, 32768, 256, 1024, 2);
  // out = LN(src + ffn_out)
  ln_kernel<0><<<8192, 256, 0, stream>>>(srcb, offbuf, gamma2, beta2, out, nullptr);
}

// Round 6
// 584.110 us; speedup vs baseline: 1.0773x; 1.0372x over previous
//
#include <hip/hip_runtime.h>

// Problem constants
#define LQN   16384     // queries per batch (128*128)
#define LINN  65536     // value length per batch (4 levels * 16384)

typedef __attribute__((ext_vector_type(8))) short bf16x8;
typedef __attribute__((ext_vector_type(4))) float f32x4;
typedef __attribute__((ext_vector_type(4))) unsigned short bf16x4;

__device__ __forceinline__ unsigned short f2bf(float f) {
  unsigned u = __float_as_uint(f);
  u += 0x7FFFu + ((u >> 16) & 1u);      // round-to-nearest-even
  return (unsigned short)(u >> 16);
}
__device__ __forceinline__ unsigned pk2bf(float lo, float hi) {
  return (unsigned)f2bf(lo) | ((unsigned)f2bf(hi) << 16);
}

// ---------------- fused weight transpose+convert for all 6 weights.
// wt layout (shorts): W_val[0,65536) W_off[65536,131072) W_attn[131072,163840)
// W_out[163840,229376) W1[229376,491520) W2[491520,753664). Total 753664.
__global__ __launch_bounds__(256) void wtrans6_kernel(
    const float* __restrict__ Wv, const float* __restrict__ Wo,
    const float* __restrict__ Wa, const float* __restrict__ Wu,
    const float* __restrict__ W1, const float* __restrict__ W2,
    unsigned short* __restrict__ wt) {
  int idx = blockIdx.x * 256 + threadIdx.x;     // grid = 2944 blocks exactly
  const float* W; int K, N, base;
  if (idx < 131072) {
    if (idx < 65536) { W = Wv; K = 256; N = 256; base = 0; }
    else             { W = Wo; K = 256; N = 256; base = 65536; }
  } else if (idx < 229376) {
    if (idx < 163840) { W = Wa; K = 256; N = 128; base = 131072; }
    else              { W = Wu; K = 256; N = 256; base = 163840; }
  } else if (idx < 491520) { W = W1; K = 256; N = 1024; base = 229376; }
  else                     { W = W2; K = 1024; N = 256; base = 491520; }
  int local = idx - base;
  int n = local / K, k = local - n * K;
  wt[idx] = f2bf(W[(size_t)k * N + n]);
}

// ---------------- qbuf = bf16(cur_src + pos[:,3]) (80 MB streaming).
__global__ __launch_bounds__(256) void addcvt_q_kernel(
    const float* __restrict__ cur, const float* __restrict__ pos,
    unsigned short* __restrict__ qb) {
  size_t j = (size_t)blockIdx.x * 256 + threadIdx.x;  // < 2,097,152 (grid 8192)
  size_t row = j >> 6;                    // n*LQ + lq
  int n = (int)(row >> 14), lq = (int)(row & 16383);
  float4 a = ((const float4*)cur)[j];
  float4 b = ((const float4*)pos)[(((size_t)n * 4 + 3) * LQN + lq) * 64 + (j & 63)];
  bf16x4 o;
  o.x = f2bf(a.x + b.x); o.y = f2bf(a.y + b.y);
  o.z = f2bf(a.z + b.z); o.w = f2bf(a.w + b.w);
  ((bf16x4*)qb)[j] = o;
}

// ---------------- fused value GEMM (v2: BM=64 for occupancy):
// value = bf16(src_all + pos_flat) @ Wv + bv, stored head-major (n,h,pix,32ch).
// M=131072, N=256 full width (f32 A-panels read exactly once), K=256, BK=64.
// 512 threads = 8 waves (2 M-groups x 4 N-groups of 32x64). LDS 40 KB ->
// 4 blocks/CU (32 waves/CU) vs 3 at BM=128: latency-bound staging needs TLP.
// A: reg-staged add+cvt (f32+f32 -> bf16), XOR-swizzled ds_write.
// B: global_load_lds with XOR source-swizzle.
__global__ __launch_bounds__(512) void gemmv_fused_kernel(
    const float* __restrict__ SA, const float* __restrict__ PS,
    const unsigned short* __restrict__ Bt, const float* __restrict__ bias,
    unsigned short* __restrict__ Cp) {
  __shared__ unsigned short As[64 * 64];    // 8 KB
  __shared__ unsigned short Bs[256 * 64];   // 32 KB
  const int m0 = blockIdx.x * 64;           // grid 2048
  const int tid = threadIdx.x;
  const int wave = tid >> 6, lane = tid & 63;
  const int wm = (wave >> 2) * 32;          // 0 or 32
  const int wn = (wave & 3) * 64;           // 0,64,128,192
  const int l15 = lane & 15, quad = lane >> 4;
  const int rl = lane >> 3;                 // row within 8-row slab (B staging)
  const int cl = (lane & 7) ^ rl;           // XOR source chunk (B staging)

  // A staging: thread owns row ar, chunk sub (8 f32 -> 8 bf16 = 16 B)
  const int ar = tid >> 3;                  // 0..63
  const int sub = tid & 7;                  // 0..7
  const float* pa = SA + (size_t)(m0 + ar) * 256 + sub * 8;
  const float* pb = PS + (size_t)(m0 + ar) * 256 + sub * 8;
  const unsigned short* Bbase = Bt + cl * 8;

  f32x4 acc[2][4];
#pragma unroll
  for (int i = 0; i < 2; i++)
#pragma unroll
    for (int j = 0; j < 4; j++)
#pragma unroll
      for (int r = 0; r < 4; r++) acc[i][j][r] = 0.f;

  for (int k0 = 0; k0 < 256; k0 += 64) {
    // B tile: async global->LDS, each wave covers 32 of 256 rows
#pragma unroll
    for (int t = 0; t < 4; t++) {
      const int row = wave * 32 + t * 8 + rl;
      __builtin_amdgcn_global_load_lds(
          (const __attribute__((address_space(1))) void*)(Bbase + (size_t)row * 256 + k0),
          (__attribute__((address_space(3))) void*)(Bs + (wave * 32 + t * 8) * 64),
          16, 0, 0);
    }
    // A tile: 2 float4 per source, add, cvt, one swizzled 16B ds_write
    float4 fa0 = ((const float4*)(pa + k0))[0];
    float4 fa1 = ((const float4*)(pa + k0))[1];
    float4 fb0 = ((const float4*)(pb + k0))[0];
    float4 fb1 = ((const float4*)(pb + k0))[1];
    uint4 wv;
    wv.x = pk2bf(fa0.x + fb0.x, fa0.y + fb0.y);
    wv.y = pk2bf(fa0.z + fb0.z, fa0.w + fb0.w);
    wv.z = pk2bf(fa1.x + fb1.x, fa1.y + fb1.y);
    wv.w = pk2bf(fa1.z + fb1.z, fa1.w + fb1.w);
    const int p = sub ^ (ar & 7);
    *(uint4*)((char*)As + ar * 128 + p * 16) = wv;
    __syncthreads();   // drains vmcnt (B) + lgkm (A writes), then barrier
#pragma unroll
    for (int kk = 0; kk < 2; kk++) {
      bf16x8 af[2], bfr[4];
#pragma unroll
      for (int i = 0; i < 2; i++) {
        const int row = wm + i * 16 + l15;
        af[i] = *(const bf16x8*)&As[row * 64 + (((quad + 4 * kk) ^ (row & 7)) * 8)];
      }
#pragma unroll
      for (int j = 0; j < 4; j++) {
        const int row = wn + j * 16 + l15;
        bfr[j] = *(const bf16x8*)&Bs[row * 64 + (((quad + 4 * kk) ^ (row & 7)) * 8)];
      }
#pragma unroll
      for (int i = 0; i < 2; i++)
#pragma unroll
        for (int j = 0; j < 4; j++)
          acc[i][j] = __builtin_amdgcn_mfma_f32_16x16x32_bf16(af[i], bfr[j], acc[i][j], 0, 0, 0);
    }
    __syncthreads();   // protect LDS before next-iter overwrite
  }
  // epilogue: bias, head-major scatter store
#pragma unroll
  for (int i = 0; i < 2; i++) {
#pragma unroll
    for (int j = 0; j < 4; j++) {
      const int col = wn + j * 16 + l15;
      const float bv = bias[col];
#pragma unroll
      for (int r = 0; r < 4; r++) {
        const int row = m0 + wm + i * 16 + quad * 4 + r;
        const float v = acc[i][j][r] + bv;
        const size_t addr = (((size_t)(row >> 16) * 8 + (col >> 5)) * 65536 +
                             (size_t)(row & 65535)) * 32 + (col & 31);
        Cp[addr] = f2bf(v);
      }
    }
  }
}

// ---------------- bf16 MFMA GEMM, m97-style global_load_lds staging.
// A: M x K bf16 row-major. Bt: N x K bf16 (pre-transposed). 128x128 tile,
// BK=64, 4 waves (2x2 of 64x64). LDS unpadded, XOR source-swizzle.
// SPLIT=1: cols [0,256) -> Cp (stride 256) + bias, cols [256,384) -> Cp2.
template <int DO_RELU, int OUT_BF16, int SPLIT>
__global__ __launch_bounds__(256) void gemm_lds_kernel(
    const unsigned short* __restrict__ A, const unsigned short* __restrict__ Bt,
    const float* __restrict__ bias, const float* __restrict__ bias2,
    void* __restrict__ Cp, float* __restrict__ Cp2,
    int M, int N, int K, int ny) {
  __shared__ unsigned short As[128 * 64];
  __shared__ unsigned short Bs[128 * 64];
  const int bid = blockIdx.x;
  const int by = bid % ny, bx = bid / ny;
  const int m0 = bx * 128, n0 = by * 128;
  const int tid = threadIdx.x;
  const int wave = tid >> 6, lane = tid & 63;
  const int wm = (wave >> 1) * 64, wn = (wave & 1) * 64;
  const int l15 = lane & 15, quad = lane >> 4;
  const int rl = lane >> 3;                 // row within 8-row slab
  const int cl = (lane & 7) ^ rl;           // swizzled source chunk (16B units)

  f32x4 acc[4][4];
#pragma unroll
  for (int i = 0; i < 4; i++)
#pragma unroll
    for (int j = 0; j < 4; j++)
#pragma unroll
      for (int r = 0; r < 4; r++) acc[i][j][r] = 0.f;

  const unsigned short* Abase = A + (size_t)m0 * K + cl * 8;
  const unsigned short* Bbase = Bt + (size_t)n0 * K + cl * 8;

  for (int k0 = 0; k0 < K; k0 += 64) {
#pragma unroll
    for (int t = 0; t < 4; t++) {
      const int row = wave * 32 + t * 8 + rl;
      __builtin_amdgcn_global_load_lds(
          (const __attribute__((address_space(1))) void*)(Abase + (size_t)row * K + k0),
          (__attribute__((address_space(3))) void*)(As + (wave * 32 + t * 8) * 64),
          16, 0, 0);
      __builtin_amdgcn_global_load_lds(
          (const __attribute__((address_space(1))) void*)(Bbase + (size_t)row * K + k0),
          (__attribute__((address_space(3))) void*)(Bs + (wave * 32 + t * 8) * 64),
          16, 0, 0);
    }
    __syncthreads();
#pragma unroll
    for (int kk = 0; kk < 2; kk++) {
      bf16x8 af[4], bfr[4];
#pragma unroll
      for (int i = 0; i < 4; i++) {
        const int row = wm + i * 16 + l15;
        af[i] = *(const bf16x8*)&As[row * 64 + (((quad + 4 * kk) ^ (row & 7)) * 8)];
      }
#pragma unroll
      for (int j = 0; j < 4; j++) {
        const int row = wn + j * 16 + l15;
        bfr[j] = *(const bf16x8*)&Bs[row * 64 + (((quad + 4 * kk) ^ (row & 7)) * 8)];
      }
#pragma unroll
      for (int i = 0; i < 4; i++)
#pragma unroll
        for (int j = 0; j < 4; j++)
          acc[i][j] = __builtin_amdgcn_mfma_f32_16x16x32_bf16(af[i], bfr[j], acc[i][j], 0, 0, 0);
    }
    __syncthreads();
  }
#pragma unroll
  for (int i = 0; i < 4; i++) {
#pragma unroll
    for (int j = 0; j < 4; j++) {
      const int col = n0 + wn + j * 16 + l15;
      float bv;
      if (SPLIT) bv = (col < 256) ? bias[col] : bias2[col - 256];
      else       bv = bias[col];
#pragma unroll
      for (int r = 0; r < 4; r++) {
        const int row = m0 + wm + i * 16 + quad * 4 + r;
        float v = acc[i][j][r] + bv;
        if (DO_RELU) v = fmaxf(v, 0.f);
        if (SPLIT) {
          if (col < 256) ((float*)Cp)[(size_t)row * 256 + col] = v;
          else           Cp2[(size_t)row * 128 + (col - 256)] = v;
        } else if (OUT_BF16) {
          ((unsigned short*)Cp)[(size_t)row * N + col] = f2bf(v);
        } else {
          ((float*)Cp)[(size_t)row * N + col] = v;
        }
      }
    }
  }
}

// ---------------- fused GEMM + residual + LayerNorm:
// outf = LN(res + A@Bt + bias) * gamma + beta   (EMIT_BF16: also bf16 copy).
// M=32768, N=256 (full row per block -> LN feasible in epilogue), BK=64,
// 512 threads = 8 waves (2M x 4N of 64x64), BM=128, grid 256.
// Epilogue: per-thread partial sums over its 4 j-cols, shfl over 16 l15
// lanes, cross-wave via small LDS arrays, then normalize + store.
template <int EMIT_BF16>
__global__ __launch_bounds__(512) void gemm_ln_kernel(
    const unsigned short* __restrict__ A, const unsigned short* __restrict__ Bt,
    const float* __restrict__ bias, const float* __restrict__ res,
    const float* __restrict__ gamma, const float* __restrict__ beta,
    float* __restrict__ outf, unsigned short* __restrict__ outb, int K) {
  __shared__ unsigned short As[128 * 64];   // 16 KB
  __shared__ unsigned short Bs[256 * 64];   // 32 KB
  __shared__ float lnred[128][4];
  __shared__ float lnsq[128][4];
  const int m0 = blockIdx.x * 128;          // grid 256
  const int tid = threadIdx.x;
  const int wave = tid >> 6, lane = tid & 63;
  const int wm = (wave >> 2) * 64;
  const int wn = (wave & 3) * 64;
  const int l15 = lane & 15, quad = lane >> 4;
  const int rl = lane >> 3;
  const int cl = (lane & 7) ^ rl;

  f32x4 acc[4][4];
#pragma unroll
  for (int i = 0; i < 4; i++)
#pragma unroll
    for (int j = 0; j < 4; j++)
#pragma unroll
      for (int r = 0; r < 4; r++) acc[i][j][r] = 0.f;

  const unsigned short* Abase = A + (size_t)m0 * K + cl * 8;
  const unsigned short* Bbase = Bt + cl * 8;

  for (int k0 = 0; k0 < K; k0 += 64) {
    // A: 128 rows, wave covers 16 (2 issues); B: 256 rows, wave covers 32
#pragma unroll
    for (int t = 0; t < 2; t++) {
      const int row = wave * 16 + t * 8 + rl;
      __builtin_amdgcn_global_load_lds(
          (const __attribute__((address_space(1))) void*)(Abase + (size_t)row * K + k0),
          (__attribute__((address_space(3))) void*)(As + (wave * 16 + t * 8) * 64),
          16, 0, 0);
    }
#pragma unroll
    for (int t = 0; t < 4; t++) {
      const int row = wave * 32 + t * 8 + rl;
      __builtin_amdgcn_global_load_lds(
          (const __attribute__((address_space(1))) void*)(Bbase + (size_t)row * K + k0),
          (__attribute__((address_space(3))) void*)(Bs + (wave * 32 + t * 8) * 64),
          16, 0, 0);
    }
    __syncthreads();
#pragma unroll
    for (int kk = 0; kk < 2; kk++) {
      bf16x8 af[4], bfr[4];
#pragma unroll
      for (int i = 0; i < 4; i++) {
        const int row = wm + i * 16 + l15;
        af[i] = *(const bf16x8*)&As[row * 64 + (((quad + 4 * kk) ^ (row & 7)) * 8)];
      }
#pragma unroll
      for (int j = 0; j < 4; j++) {
        const int row = wn + j * 16 + l15;
        bfr[j] = *(const bf16x8*)&Bs[row * 64 + (((quad + 4 * kk) ^ (row & 7)) * 8)];
      }
#pragma unroll
      for (int i = 0; i < 4; i++)
#pragma unroll
        for (int j = 0; j < 4; j++)
          acc[i][j] = __builtin_amdgcn_mfma_f32_16x16x32_bf16(af[i], bfr[j], acc[i][j], 0, 0, 0);
    }
    __syncthreads();
  }

  // ---- epilogue: u = acc + bias + res; LN over 256 cols per row
  float s1[4][4], s2[4][4];
#pragma unroll
  for (int i = 0; i < 4; i++)
#pragma unroll
    for (int r = 0; r < 4; r++) { s1[i][r] = 0.f; s2[i][r] = 0.f; }
#pragma unroll
  for (int i = 0; i < 4; i++) {
#pragma unroll
    for (int j = 0; j < 4; j++) {
      const int col = wn + j * 16 + l15;
      const float bv = bias[col];
#pragma unroll
      for (int r = 0; r < 4; r++) {
        const int rloc = wm + i * 16 + quad * 4 + r;
        const size_t grow = (size_t)(m0 + rloc);
        float u = acc[i][j][r] + bv + res[grow * 256 + col];
        acc[i][j][r] = u;
        s1[i][r] += u; s2[i][r] += u * u;
      }
    }
  }
  // reduce over the 16 l15-lanes sharing each row (xor of bits 0..3)
#pragma unroll
  for (int o = 1; o < 16; o <<= 1) {
#pragma unroll
    for (int i = 0; i < 4; i++)
#pragma unroll
      for (int r = 0; r < 4; r++) {
        s1[i][r] += __shfl_xor(s1[i][r], o);
        s2[i][r] += __shfl_xor(s2[i][r], o);
      }
  }
  if (l15 == 0) {
#pragma unroll
    for (int i = 0; i < 4; i++)
#pragma unroll
      for (int r = 0; r < 4; r++) {
        const int rloc = wm + i * 16 + quad * 4 + r;
        lnred[rloc][wave & 3] = s1[i][r];
        lnsq[rloc][wave & 3] = s2[i][r];
      }
  }
  __syncthreads();
#pragma unroll
  for (int i = 0; i < 4; i++) {
#pragma unroll
    for (int r = 0; r < 4; r++) {
      const int rloc = wm + i * 16 + quad * 4 + r;
      const float S1 = lnred[rloc][0] + lnred[rloc][1] + lnred[rloc][2] + lnred[rloc][3];
      const float S2 = lnsq[rloc][0] + lnsq[rloc][1] + lnsq[rloc][2] + lnsq[rloc][3];
      const float mean = S1 * (1.f / 256.f);
      const float rstd = rsqrtf(S2 * (1.f / 256.f) - mean * mean + 1e-5f);
      const size_t grow = (size_t)(m0 + rloc);
#pragma unroll
      for (int j = 0; j < 4; j++) {
        const int col = wn + j * 16 + l15;
        const float o = (acc[i][j][r] - mean) * rstd * gamma[col] + beta[col];
        outf[grow * 256 + col] = o;
        if (EMIT_BF16) outb[grow * 256 + col] = f2bf(o);
      }
    }
  }
}

// ---------------- deformable sampling (v3) — unchanged from R3 (verified)
// value: (2, 8, LINN, 32) bf16 head-major; 8-lane subgroup per (n,lq,h);
// head-major block order; 128 B pixel-pair dwordx4 gathers; LDS stride 132.
__global__ __launch_bounds__(256) void sample_kernel(
    const unsigned short* __restrict__ value, const float* __restrict__ offs,
    const float* __restrict__ attnl, const float* __restrict__ refp,
    unsigned int* __restrict__ attn_out) {
  __shared__ float wlds[32][132];
  const int tid = threadIdx.x;
  const int sub = tid >> 3;                // 0..31
  const int cl  = tid & 7;                 // lane in subgroup
  const int gb = blockIdx.x * 32 + sub;    // head-major linear id, < 262144
  const int h  = gb >> 15;                 // head (uniform per block)
  const int nl = gb & 32767;               // n*LQ + lq
  const int n  = nl >> 14;
  const int g  = nl * 8 + h;               // row id in offs / attn_out

  const float* lg = attnl + (size_t)nl * 128 + h * 16;
  const float2 l2 = *(const float2*)(lg + 2 * cl);
  float mx = fmaxf(l2.x, l2.y);
#pragma unroll
  for (int o = 1; o < 8; o <<= 1) mx = fmaxf(mx, __shfl_xor(mx, o, 8));
  const float e0 = __expf(l2.x - mx), e1 = __expf(l2.y - mx);
  float s = e0 + e1;
#pragma unroll
  for (int o = 1; o < 8; o <<= 1) s += __shfl_xor(s, o, 8);
  const float inv = 1.f / s;

  const float4 o4 = *(const float4*)(offs + (size_t)g * 32 + 4 * cl);
  const float2 r2 = *(const float2*)(refp + ((size_t)nl * 4 + (cl >> 1)) * 2);
#pragma unroll
  for (int q = 0; q < 2; q++) {
    const float ox = (q == 0) ? o4.x : o4.z;
    const float oy = (q == 0) ? o4.y : o4.w;
    const float aw = ((q == 0) ? e0 : e1) * inv;
    const float x = fmaf(r2.x, 128.f, ox - 0.5f);   // (ref + off/128)*128 - 0.5
    const float y = fmaf(r2.y, 128.f, oy - 0.5f);
    const float xf = floorf(x), yf = floorf(y);
    const float fx = x - xf, fy = y - yf;
    const int x0 = (int)xf, y0 = (int)yf;
    const float wx0 = (x0 >= 0 && x0 <= 127) ? (1.f - fx) : 0.f;
    const float wx1 = (x0 >= -1 && x0 <= 126) ? fx : 0.f;
    const float wy0 = ((y0 >= 0 && y0 <= 127) ? (1.f - fy) : 0.f) * aw;
    const float wy1 = ((y0 >= -1 && y0 <= 126) ? fy : 0.f) * aw;
    const int px = min(max(x0, 0), 126);
    const float wl = (px == x0) ? wx0 : ((px == x0 + 1) ? wx1 : 0.f);
    const float wr = (px + 1 == x0) ? wx0 : ((px == x0) ? wx1 : 0.f);
    const int yc0 = min(max(y0, 0), 127), yc1 = min(max(y0 + 1, 0), 127);
    const int lb = (cl >> 1) * 16384;
    const unsigned ot = (unsigned)(lb + yc0 * 128 + px) * 64u;  // byte offsets
    const unsigned ob = (unsigned)(lb + yc1 * 128 + px) * 64u;
    float* wp = &wlds[sub][(2 * cl + q) * 8];
    wp[0] = wl * wy0; wp[1] = wr * wy0;
    wp[2] = wl * wy1; wp[3] = wr * wy1;
    wp[4] = __uint_as_float(ot); wp[5] = __uint_as_float(ob);
  }

  const char* hb = (const char*)value + (((size_t)(n * 8 + h)) << 22) + cl * 16;
  float a0 = 0.f, a1 = 0.f, a2 = 0.f, a3 = 0.f;
  float a4 = 0.f, a5 = 0.f, a6 = 0.f, a7 = 0.f;
#pragma unroll
  for (int p = 0; p < 16; p++) {
    const float4 w4 = *(const float4*)&wlds[sub][p * 8];
    const float2 of2 = *(const float2*)&wlds[sub][p * 8 + 4];
    const uint4 vt = *(const uint4*)(hb + __float_as_uint(of2.x));
    const uint4 vb = *(const uint4*)(hb + __float_as_uint(of2.y));
    const float wtop = (cl < 4) ? w4.x : w4.y;
    const float wbot = (cl < 4) ? w4.z : w4.w;
#define ACC8(vv, wgt)                                              \
    a0 = fmaf(wgt, __uint_as_float((vv).x << 16), a0);             \
    a1 = fmaf(wgt, __uint_as_float((vv).x & 0xFFFF0000u), a1);     \
    a2 = fmaf(wgt, __uint_as_float((vv).y << 16), a2);             \
    a3 = fmaf(wgt, __uint_as_float((vv).y & 0xFFFF0000u), a3);     \
    a4 = fmaf(wgt, __uint_as_float((vv).z << 16), a4);             \
    a5 = fmaf(wgt, __uint_as_float((vv).z & 0xFFFF0000u), a5);     \
    a6 = fmaf(wgt, __uint_as_float((vv).w << 16), a6);             \
    a7 = fmaf(wgt, __uint_as_float((vv).w & 0xFFFF0000u), a7);
    ACC8(vt, wtop)
    ACC8(vb, wbot)
#undef ACC8
  }
  a0 += __shfl_xor(a0, 4, 8); a1 += __shfl_xor(a1, 4, 8);
  a2 += __shfl_xor(a2, 4, 8); a3 += __shfl_xor(a3, 4, 8);
  a4 += __shfl_xor(a4, 4, 8); a5 += __shfl_xor(a5, 4, 8);
  a6 += __shfl_xor(a6, 4, 8); a7 += __shfl_xor(a7, 4, 8);
  if (cl < 4) {
    uint4 o;
    o.x = (unsigned)f2bf(a0) | ((unsigned)f2bf(a1) << 16);
    o.y = (unsigned)f2bf(a2) | ((unsigned)f2bf(a3) << 16);
    o.z = (unsigned)f2bf(a4) | ((unsigned)f2bf(a5) << 16);
    o.w = (unsigned)f2bf(a6) | ((unsigned)f2bf(a7) << 16);
    ((uint4*)attn_out)[(size_t)g * 4 + cl] = o;
  }
}

extern "C" void kernel_launch(void* const* d_in, const int* in_sizes, int n_in,
                              void* d_out, int out_size, void* d_ws, size_t ws_size,
                              hipStream_t stream) {
  (void)in_sizes; (void)n_in; (void)out_size; (void)ws_size;
  const float* cur_src = (const float*)d_in[0];
  const float* src_all = (const float*)d_in[1];
  const float* pos     = (const float*)d_in[2];
  const float* refp    = (const float*)d_in[3];
  const float* W_off   = (const float*)d_in[6];
  const float* b_off   = (const float*)d_in[7];
  const float* W_attn  = (const float*)d_in[8];
  const float* b_attn  = (const float*)d_in[9];
  const float* W_val   = (const float*)d_in[10];
  const float* b_val   = (const float*)d_in[11];
  const float* W_out   = (const float*)d_in[12];
  const float* b_out   = (const float*)d_in[13];
  const float* gamma1  = (const float*)d_in[14];
  const float* beta1   = (const float*)d_in[15];
  const float* W1      = (const float*)d_in[16];
  const float* b1      = (const float*)d_in[17];
  const float* W2      = (const float*)d_in[18];
  const float* b2      = (const float*)d_in[19];
  const float* gamma2  = (const float*)d_in[20];
  const float* beta2   = (const float*)d_in[21];
  float* out = (float*)d_out;

  // workspace layout (bytes)
  char* ws = (char*)d_ws;
  unsigned short* value = (unsigned short*)(ws + 0);          // 64 MiB; reused as FFN hidden
  unsigned short* qbuf  = (unsigned short*)(ws + 67108864);   // 16 MiB
  float* offbuf         = (float*)(ws + 83886080);            // 32 MiB
  float* attnl          = (float*)(ws + 117440512);           // 16 MiB; reused as srcb_bf16
  unsigned short* attno = (unsigned short*)(ws + 134217728);  // 16 MiB
  float* srcb           = (float*)(ws + 184549376);           // 32 MiB
  unsigned short* wt    = (unsigned short*)(ws + 218103808);  // bf16 weights (1.5 MB)
  unsigned short* wt_val  = wt;
  unsigned short* wt_qa   = wt + 65536;   // W_off(256xK) ++ W_attn(128xK) contiguous
  unsigned short* wt_out  = wt + 163840;
  unsigned short* wt_1    = wt + 229376;
  unsigned short* wt_2    = wt + 491520;
  unsigned short* srcb_bf = (unsigned short*)attnl;           // attnl dead after sample

  // prep: all weights -> bf16 NxK in one launch
  wtrans6_kernel<<<2944, 256, 0, stream>>>(W_val, W_off, W_attn, W_out, W1, W2, wt);

  // qbuf = bf16(cur_src + pos[:,3])
  addcvt_q_kernel<<<8192, 256, 0, stream>>>(cur_src, pos, qbuf);

  // value = bf16(src_all + pos) @ W_val + b_val -> bf16 head-major (fused, BM=64)
  gemmv_fused_kernel<<<2048, 512, 0, stream>>>(src_all, pos, wt_val, b_val, value);

  // [off | attn logits] = qbuf @ [W_off | W_attn] (merged N=384, split epilogue)
  gemm_lds_kernel<0, 0, 1><<<768, 256, 0, stream>>>(
      qbuf, wt_qa, b_off, b_attn, offbuf, attnl, 32768, 384, 256, 3);
  // deformable sampling -> attn_out bf16 (head-major block order)
  sample_kernel<<<8192, 256, 0, stream>>>(value, offbuf, attnl, refp,
                                          (unsigned int*)attno);
  // src = LN(cur_src + attno@W_out + b_out) -> f32 srcb + bf16 srcb_bf (fused)
  gemm_ln_kernel<1><<<256, 512, 0, stream>>>(
      attno, wt_out, b_out, cur_src, gamma1, beta1, srcb, srcb_bf, 256);
  // h = relu(src @ W1 + b1) -> bf16 (reuses value buffer)
  gemm_lds_kernel<1, 1, 0><<<2048, 256, 0, stream>>>(
      srcb_bf, wt_1, b1, nullptr, value, nullptr, 32768, 1024, 256, 8);
  // out = LN(srcb + h@W2 + b2) (fused, K=1024)
  gemm_ln_kernel<0><<<256, 512, 0, stream>>>(
      value, wt_2, b2, srcb, gamma2, beta2, out, nullptr, 1024);
}